// Round 6
// baseline (2676.532 us; speedup 1.0000x reference)
//
#include <hip/hip_runtime.h>
#include <cmath>

#define NT 256

// fp32 BatchNorm(eval)+ReLU, XLA-faithful rounding (verified bit-exact r5):
// rsqrt = fdiv(1, sqrtf(v+eps)) correctly rounded (via fp64), uncontracted ops.
__device__ __forceinline__ float bn_relu32(float h, float g, float b, float m, float v) {
#pragma clang fp contract(off)
    float vp = v + 1e-5f;
    float sq = (float)sqrt((double)vp);
    float rs = (float)(1.0 / (double)sq);
    float t = ((h - m) * rs) * g + b;
    return fmaxf(t, 0.0f);
}

// exp-form logistic + clip + step (verified bit-exact r5)
__device__ __forceinline__ float hard_gate(float x) {
#pragma clang fp contract(off)
    float e = (float)exp((double)(-x));     // correctly-rounded fp32 expf
    float d = 1.0f + e;
    float sg = (float)(1.0 / (double)d);    // correctly-rounded fp32 div
    float s = 1.2f * sg - 0.1f;
    s = fminf(fmaxf(s, 0.0f), 1.0f);
    return (s > 0.49999f) ? 1.0f : 0.0f;
}

// One layer, loop-swapped for ILP: thread owns CPT columns (n, n+NT, ...) and
// RPT rows (r0 + i*rstep). Per k-quad: W float4 per column loaded ONCE into
// registers, A row values broadcast-read from LDS (wave-uniform addr), then
// CPT*RPT independent fma chains. Per-output accumulation stays a single
// accumulator with strictly ascending k -> bit-identical to verified dotk.
// EPI 1: BN+ReLU -> LDS.  EPI 2: hard gate -> global.
template<int CPT, int RPT, int EPI>
__device__ __forceinline__ void layer(
    const float* __restrict__ I, int ldI, int K,
    const float* __restrict__ Wt, long ldW,
    const float* __restrict__ Pg, const float* __restrict__ Pb,
    const float* __restrict__ Pm, const float* __restrict__ Pv,
    float* __restrict__ O, int ldO,
    int n, int r0, int rstep)
{
    float acc[CPT][RPT];
#pragma unroll
    for (int c = 0; c < CPT; ++c)
#pragma unroll
        for (int r = 0; r < RPT; ++r) acc[c][r] = 0.0f;

    for (int k = 0; k < K; k += 4) {
        float4 av[RPT];
#pragma unroll
        for (int r = 0; r < RPT; ++r)
            av[r] = *reinterpret_cast<const float4*>(I + (r0 + r * rstep) * ldI + k);
#pragma unroll
        for (int c = 0; c < CPT; ++c) {
            float4 w = *reinterpret_cast<const float4*>(Wt + (long)(n + c * NT) * ldW + k);
#pragma unroll
            for (int r = 0; r < RPT; ++r) {
                acc[c][r] = fmaf(av[r].x, w.x, acc[c][r]);
                acc[c][r] = fmaf(av[r].y, w.y, acc[c][r]);
                acc[c][r] = fmaf(av[r].z, w.z, acc[c][r]);
                acc[c][r] = fmaf(av[r].w, w.w, acc[c][r]);
            }
        }
    }

#pragma unroll
    for (int c = 0; c < CPT; ++c) {
        int nn = n + c * NT;
        if constexpr (EPI == 1) {
            float gg = Pg[nn], bb = Pb[nn], mm = Pm[nn], vv = Pv[nn];
#pragma unroll
            for (int r = 0; r < RPT; ++r)
                O[(r0 + r * rstep) * ldO + nn] = bn_relu32(acc[c][r], gg, bb, mm, vv);
        } else {
#pragma unroll
            for (int r = 0; r < RPT; ++r)
                O[(r0 + r * rstep) * ldO + nn] = hard_gate(acc[c][r]);
        }
    }
}

// Whole network, 8 batch rows per block, fp32 intermediates in 48 KB LDS.
__global__ __launch_bounds__(NT)
void tg32(const float* __restrict__ prompt,
    const float* __restrict__ W1, const float* __restrict__ g1, const float* __restrict__ b1, const float* __restrict__ m1, const float* __restrict__ v1,
    const float* __restrict__ W2, const float* __restrict__ g2, const float* __restrict__ b2, const float* __restrict__ m2, const float* __restrict__ v2,
    const float* __restrict__ W3, const float* __restrict__ g3, const float* __restrict__ b3, const float* __restrict__ m3, const float* __restrict__ v3,
    const float* __restrict__ W4, const float* __restrict__ g4, const float* __restrict__ b4, const float* __restrict__ m4, const float* __restrict__ v4,
    const float* __restrict__ We1, const float* __restrict__ We2,
    const float* __restrict__ eg, const float* __restrict__ eb, const float* __restrict__ em, const float* __restrict__ ev,
    float* __restrict__ out)
{
    __shared__ __align__(16) float arena[12288];   // 48 KB -> 3 blocks/CU
    float* A0 = arena;            // 8x512  : prompt -> h2 -> h4
    float* A1 = arena + 4096;     // 8x1024 : h3 ; overlaid: H1 (8x64), XG (8x256)
    float* H1 = A1;
    float* XG = A1;

    const int t = threadIdx.x;
    const long row0 = (long)blockIdx.x * 8;

    for (int i = t; i < 1024; i += NT) {          // stage prompt 8x512
        int r = i >> 7, c4 = (i & 127) << 2;
        *reinterpret_cast<float4*>(A0 + r * 512 + c4) =
            *reinterpret_cast<const float4*>(prompt + (row0 + r) * 512 + c4);
    }
    __syncthreads();

    // L1: [8,512] -> [8,64]   (n = t&63, rows {t>>6, t>>6+4})
    layer<1, 2, 1>(A0, 512, 512, W1, 512, g1, b1, m1, v1, H1, 64, t & 63, t >> 6, 4);
    __syncthreads();
    // L2: [8,64] -> [8,512]   (over prompt)
    layer<2, 8, 1>(H1, 64, 64, W2, 64, g2, b2, m2, v2, A0, 512, t, 0, 1);
    __syncthreads();
    // L3: [8,512] -> [8,1024] (over H1 region; H1 dead)
    layer<4, 8, 1>(A0, 512, 512, W3, 512, g3, b3, m3, v3, A1, 1024, t, 0, 1);
    __syncthreads();
    // L4: [8,1024] -> [8,512] (over h2)
    layer<2, 8, 1>(A1, 1024, 1024, W4, 1024, g4, b4, m4, v4, A0, 512, t, 0, 1);
    __syncthreads();

    for (int g = 0; g < 8; ++g) {
        // L5: h4[:, g*64..+64) -> XG [8,256], expert-0 BN row g
        layer<1, 8, 1>(A0 + g * 64, 512, 64, We1, 64,
                       eg + g * 256, eb + g * 256, em + g * 256, ev + g * 256,
                       XG, 256, t, 0, 1);
        __syncthreads();
        // L6: XG -> hard gate -> out[row, g*64..+64)
        layer<1, 2, 2>(XG, 256, 256, We2, 256, nullptr, nullptr, nullptr, nullptr,
                       out + row0 * 512 + g * 64, 512, t & 63, t >> 6, 4);
        __syncthreads();
    }
}

extern "C" void kernel_launch(void* const* d_in, const int* in_sizes, int n_in,
                              void* d_out, int out_size, void* d_ws, size_t ws_size,
                              hipStream_t stream) {
    (void)n_in; (void)out_size; (void)d_ws; (void)ws_size;
    const float* prompt = (const float*)d_in[0];
    const float* W1 = (const float*)d_in[1];
    const float* g1 = (const float*)d_in[2];
    const float* b1 = (const float*)d_in[3];
    const float* m1 = (const float*)d_in[4];
    const float* v1 = (const float*)d_in[5];
    const float* W2 = (const float*)d_in[6];
    const float* g2 = (const float*)d_in[7];
    const float* b2 = (const float*)d_in[8];
    const float* m2 = (const float*)d_in[9];
    const float* v2 = (const float*)d_in[10];
    const float* W3 = (const float*)d_in[11];
    const float* g3 = (const float*)d_in[12];
    const float* b3 = (const float*)d_in[13];
    const float* m3 = (const float*)d_in[14];
    const float* v3 = (const float*)d_in[15];
    const float* W4 = (const float*)d_in[16];
    const float* g4 = (const float*)d_in[17];
    const float* b4 = (const float*)d_in[18];
    const float* m4 = (const float*)d_in[19];
    const float* v4 = (const float*)d_in[20];
    const float* We1 = (const float*)d_in[21];
    const float* We2 = (const float*)d_in[22];
    const float* eg = (const float*)d_in[23];
    const float* eb = (const float*)d_in[24];
    const float* em = (const float*)d_in[25];
    const float* ev = (const float*)d_in[26];
    float* out = (float*)d_out;

    const int Btot = in_sizes[0] / 512;          // 16384
    tg32<<<dim3(Btot / 8), dim3(NT), 0, stream>>>(prompt,
        W1, g1, b1, m1, v1, W2, g2, b2, m2, v2,
        W3, g3, b3, m3, v3, W4, g4, b4, m4, v4,
        We1, We2, eg, eb, em, ev, out);
}

// Round 7
// 2522.930 us; speedup vs baseline: 1.0609x; 1.0609x over previous
//
#include <hip/hip_runtime.h>
#include <cmath>

#define NT 512

// fp32 BatchNorm(eval)+ReLU, XLA-faithful rounding (verified bit-exact r5/r6):
// rsqrt = fdiv(1, sqrtf(v+eps)) correctly rounded (via fp64), uncontracted ops.
__device__ __forceinline__ float bn_relu32(float h, float g, float b, float m, float v) {
#pragma clang fp contract(off)
    float vp = v + 1e-5f;
    float sq = (float)sqrt((double)vp);
    float rs = (float)(1.0 / (double)sq);
    float t = ((h - m) * rs) * g + b;
    return fmaxf(t, 0.0f);
}

// exp-form logistic + clip + step (verified bit-exact r5/r6)
__device__ __forceinline__ float hard_gate(float x) {
#pragma clang fp contract(off)
    float e = (float)exp((double)(-x));     // correctly-rounded fp32 expf
    float d = 1.0f + e;
    float sg = (float)(1.0 / (double)d);    // correctly-rounded fp32 div
    float s = 1.2f * sg - 0.1f;
    s = fminf(fmaxf(s, 0.0f), 1.0f);
    return (s > 0.49999f) ? 1.0f : 0.0f;
}

// One layer, loop-swapped for ILP: thread owns CPT columns (n + c*NT) and RPT
// rows (r0 + i*rstep). Per k-quad: W float4 per column loaded once, A row
// values broadcast-read from LDS (wave-uniform addr -> conflict-free), then
// CPT*RPT independent fma chains. Per-output accumulation: single accumulator,
// strictly ascending k, IEEE fmaf -> bit-identical to the verified recipe.
// EPI 1: BN+ReLU -> LDS.  EPI 2: hard gate -> global.
template<int CPT, int RPT, int EPI>
__device__ __forceinline__ void layer(
    const float* __restrict__ I, int ldI, int K,
    const float* __restrict__ Wt, long ldW,
    const float* __restrict__ Pg, const float* __restrict__ Pb,
    const float* __restrict__ Pm, const float* __restrict__ Pv,
    float* __restrict__ O, int ldO,
    int n, int r0, int rstep)
{
    float acc[CPT][RPT];
#pragma unroll
    for (int c = 0; c < CPT; ++c)
#pragma unroll
        for (int r = 0; r < RPT; ++r) acc[c][r] = 0.0f;

#pragma unroll 2
    for (int k = 0; k < K; k += 4) {
        float4 av[RPT];
#pragma unroll
        for (int r = 0; r < RPT; ++r)
            av[r] = *reinterpret_cast<const float4*>(I + (r0 + r * rstep) * ldI + k);
#pragma unroll
        for (int c = 0; c < CPT; ++c) {
            float4 w = *reinterpret_cast<const float4*>(Wt + (long)(n + c * NT) * ldW + k);
#pragma unroll
            for (int r = 0; r < RPT; ++r) {
                acc[c][r] = fmaf(av[r].x, w.x, acc[c][r]);
                acc[c][r] = fmaf(av[r].y, w.y, acc[c][r]);
                acc[c][r] = fmaf(av[r].z, w.z, acc[c][r]);
                acc[c][r] = fmaf(av[r].w, w.w, acc[c][r]);
            }
        }
    }

#pragma unroll
    for (int c = 0; c < CPT; ++c) {
        int nn = n + c * NT;
        if constexpr (EPI == 1) {
            float gg = Pg[nn], bb = Pb[nn], mm = Pm[nn], vv = Pv[nn];
#pragma unroll
            for (int r = 0; r < RPT; ++r)
                O[(r0 + r * rstep) * ldO + nn] = bn_relu32(acc[c][r], gg, bb, mm, vv);
        } else {
#pragma unroll
            for (int r = 0; r < RPT; ++r)
                O[(r0 + r * rstep) * ldO + nn] = hard_gate(acc[c][r]);
        }
    }
}

// Whole network, 8 batch rows per block, 512 threads, fp32 in 48 KB LDS.
// __launch_bounds__(512,4): cap VGPR at 128 (4 waves/EU) -> no spills,
// 2 blocks/CU (LDS 96/160 KB) = 16 waves/CU = 50% occupancy.
__global__ __launch_bounds__(NT, 4)
void tg32(const float* __restrict__ prompt,
    const float* __restrict__ W1, const float* __restrict__ g1, const float* __restrict__ b1, const float* __restrict__ m1, const float* __restrict__ v1,
    const float* __restrict__ W2, const float* __restrict__ g2, const float* __restrict__ b2, const float* __restrict__ m2, const float* __restrict__ v2,
    const float* __restrict__ W3, const float* __restrict__ g3, const float* __restrict__ b3, const float* __restrict__ m3, const float* __restrict__ v3,
    const float* __restrict__ W4, const float* __restrict__ g4, const float* __restrict__ b4, const float* __restrict__ m4, const float* __restrict__ v4,
    const float* __restrict__ We1, const float* __restrict__ We2,
    const float* __restrict__ eg, const float* __restrict__ eb, const float* __restrict__ em, const float* __restrict__ ev,
    float* __restrict__ out)
{
    __shared__ __align__(16) float arena[12288];   // 48 KB
    float* A0 = arena;            // 8x512  : prompt -> h2 -> h4
    float* A1 = arena + 4096;     // 8x1024 : h3 ; overlaid: H1 (8x64), XG (8x256)
    float* H1 = A1;
    float* XG = A1;

    const int t = threadIdx.x;
    const long row0 = (long)blockIdx.x * 8;

    for (int i = t; i < 1024; i += NT) {          // stage prompt 8x512
        int r = i >> 7, c4 = (i & 127) << 2;
        *reinterpret_cast<float4*>(A0 + r * 512 + c4) =
            *reinterpret_cast<const float4*>(prompt + (row0 + r) * 512 + c4);
    }
    __syncthreads();

    // L1: [8,512] -> [8,64]   64x8 outputs / 512 thr: n=t&63, row=t>>6
    layer<1, 1, 1>(A0, 512, 512, W1, 512, g1, b1, m1, v1, H1, 64, t & 63, t >> 6, 1);
    __syncthreads();
    // L2: [8,64] -> [8,512]   512x8 / 512: n=t, all 8 rows
    layer<1, 8, 1>(H1, 64, 64, W2, 64, g2, b2, m2, v2, A0, 512, t, 0, 1);
    __syncthreads();
    // L3: [8,512] -> [8,1024] 1024x8 / 512: n={t, t+512}, all 8 rows
    layer<2, 8, 1>(A0, 512, 512, W3, 512, g3, b3, m3, v3, A1, 1024, t, 0, 1);
    __syncthreads();
    // L4: [8,1024] -> [8,512] 512x8 / 512: n=t, all 8 rows
    layer<1, 8, 1>(A1, 1024, 1024, W4, 1024, g4, b4, m4, v4, A0, 512, t, 0, 1);
    __syncthreads();

    for (int g = 0; g < 8; ++g) {
        // L5: h4[:, g*64..+64) -> XG [8,256]  256x8 / 512: n=t&255, rows (t>>8)*4..+3
        layer<1, 4, 1>(A0 + g * 64, 512, 64, We1, 64,
                       eg + g * 256, eb + g * 256, em + g * 256, ev + g * 256,
                       XG, 256, t & 255, (t >> 8) * 4, 1);
        __syncthreads();
        // L6: XG -> hard gate -> out[row, g*64..+64)  64x8 / 512: n=t&63, row=t>>6
        layer<1, 1, 2>(XG, 256, 256, We2, 256, nullptr, nullptr, nullptr, nullptr,
                       out + row0 * 512 + g * 64, 512, t & 63, t >> 6, 1);
        __syncthreads();
    }
}

extern "C" void kernel_launch(void* const* d_in, const int* in_sizes, int n_in,
                              void* d_out, int out_size, void* d_ws, size_t ws_size,
                              hipStream_t stream) {
    (void)n_in; (void)out_size; (void)d_ws; (void)ws_size;
    const float* prompt = (const float*)d_in[0];
    const float* W1 = (const float*)d_in[1];
    const float* g1 = (const float*)d_in[2];
    const float* b1 = (const float*)d_in[3];
    const float* m1 = (const float*)d_in[4];
    const float* v1 = (const float*)d_in[5];
    const float* W2 = (const float*)d_in[6];
    const float* g2 = (const float*)d_in[7];
    const float* b2 = (const float*)d_in[8];
    const float* m2 = (const float*)d_in[9];
    const float* v2 = (const float*)d_in[10];
    const float* W3 = (const float*)d_in[11];
    const float* g3 = (const float*)d_in[12];
    const float* b3 = (const float*)d_in[13];
    const float* m3 = (const float*)d_in[14];
    const float* v3 = (const float*)d_in[15];
    const float* W4 = (const float*)d_in[16];
    const float* g4 = (const float*)d_in[17];
    const float* b4 = (const float*)d_in[18];
    const float* m4 = (const float*)d_in[19];
    const float* v4 = (const float*)d_in[20];
    const float* We1 = (const float*)d_in[21];
    const float* We2 = (const float*)d_in[22];
    const float* eg = (const float*)d_in[23];
    const float* eb = (const float*)d_in[24];
    const float* em = (const float*)d_in[25];
    const float* ev = (const float*)d_in[26];
    float* out = (float*)d_out;

    const int Btot = in_sizes[0] / 512;          // 16384
    tg32<<<dim3(Btot / 8), dim3(NT), 0, stream>>>(prompt,
        W1, g1, b1, m1, v1, W2, g2, b2, m2, v2,
        W3, g3, b3, m3, v3, W4, g4, b4, m4, v4,
        We1, We2, eg, eb, em, ev, out);
}

// Round 8
// 1252.270 us; speedup vs baseline: 2.1373x; 2.0147x over previous
//
#include <hip/hip_runtime.h>
#include <cmath>

// ---------------------------------------------------------------------------
// Verified bit-exact numerics (r5/r6/r7): fp32, uncontracted, correctly-rounded
// sqrt/div/exp via fp64 helpers; ascending-k single-accumulator fmaf chains.
// ---------------------------------------------------------------------------
__device__ __forceinline__ float bn_relu32(float h, float g, float b, float m, float v) {
#pragma clang fp contract(off)
    float vp = v + 1e-5f;
    float sq = (float)sqrt((double)vp);
    float rs = (float)(1.0 / (double)sq);
    float t = ((h - m) * rs) * g + b;
    return fmaxf(t, 0.0f);
}

__device__ __forceinline__ float hard_gate(float x) {
#pragma clang fp contract(off)
    float e = (float)exp((double)(-x));
    float d = 1.0f + e;
    float sg = (float)(1.0 / (double)d);
    float s = 1.2f * sg - 0.1f;
    s = fminf(fmaxf(s, 0.0f), 1.0f);
    return (s > 0.49999f) ? 1.0f : 0.0f;
}

// ---------------------------------------------------------------------------
// Tiled fp32 GEMM + fused epilogue.  C[z][m][n] = epi( A[z][m][:] . W[n][:] )
// BM x BN block tile, BK=16, 256 threads, TM x TN micro-tile.
// A,W staged in LDS coalesced; inner loop strictly ascending k, single
// accumulator per output -> bit-identical to the verified dotk recipe.
// EPI 1: BatchNorm+ReLU (params at n + pZ*z).  EPI 2: hard gate.
// ---------------------------------------------------------------------------
template<int BM, int BN, int TM, int TN, int EPI>
__global__ __launch_bounds__(256, 4)
void gemm_lbr(const float* __restrict__ A, long lda, long aZ,
              const float* __restrict__ W, long ldw,
              const float* __restrict__ Pg, const float* __restrict__ Pb,
              const float* __restrict__ Pm, const float* __restrict__ Pv, long pZ,
              float* __restrict__ C, long ldc, long cZ, int K)
{
    constexpr int BK = 16, PAD = 4, NT = 256;
    __shared__ float As[BK][BM + PAD];
    __shared__ float Bs[BK][BN + PAD];

    const int t = threadIdx.x;
    const long m0 = (long)blockIdx.y * BM;
    const int n0 = blockIdx.x * BN;
    const int z = blockIdx.z;
    const float* Ab = A + (long)z * aZ + m0 * lda;
    const float* Wb = W + (long)n0 * ldw;

    const int tx = t % (BN / TN);
    const int ty = t / (BN / TN);

    float acc[TM][TN];
#pragma unroll
    for (int i = 0; i < TM; ++i)
#pragma unroll
        for (int j = 0; j < TN; ++j) acc[i][j] = 0.0f;

    for (int k0 = 0; k0 < K; k0 += BK) {
        // stage A tile (BM x BK), coalesced 64B-line reads, transposed store
#pragma unroll
        for (int i = 0; i < (BM * BK) / (4 * NT); ++i) {
            int idx = t + i * NT;
            int m = idx >> 2, kq = (idx & 3) << 2;
            float4 v = *reinterpret_cast<const float4*>(Ab + m * lda + k0 + kq);
            As[kq + 0][m] = v.x; As[kq + 1][m] = v.y;
            As[kq + 2][m] = v.z; As[kq + 3][m] = v.w;
        }
        // stage W tile (BN x BK)
#pragma unroll
        for (int i = 0; i < (BN * BK) / (4 * NT); ++i) {
            int idx = t + i * NT;
            int n = idx >> 2, kq = (idx & 3) << 2;
            float4 v = *reinterpret_cast<const float4*>(Wb + n * ldw + k0 + kq);
            Bs[kq + 0][n] = v.x; Bs[kq + 1][n] = v.y;
            Bs[kq + 2][n] = v.z; Bs[kq + 3][n] = v.w;
        }
        __syncthreads();

#pragma unroll
        for (int kk = 0; kk < BK; ++kk) {
            float a[TM], b[TN];
#pragma unroll
            for (int i = 0; i < TM; i += 4)
                *reinterpret_cast<float4*>(&a[i]) =
                    *reinterpret_cast<const float4*>(&As[kk][ty * TM + i]);
#pragma unroll
            for (int j = 0; j < TN; j += 4)
                *reinterpret_cast<float4*>(&b[j]) =
                    *reinterpret_cast<const float4*>(&Bs[kk][tx * TN + j]);
#pragma unroll
            for (int i = 0; i < TM; ++i)
#pragma unroll
                for (int j = 0; j < TN; ++j)
                    acc[i][j] = fmaf(a[i], b[j], acc[i][j]);
        }
        __syncthreads();
    }

    float* Cb = C + (long)z * cZ + (m0 + ty * TM) * ldc + n0 + tx * TN;
#pragma unroll
    for (int j = 0; j < TN; ++j) {
        int nn = n0 + tx * TN + j;
        if constexpr (EPI == 1) {
            long p = (long)z * pZ + nn;
            float gg = Pg[p], bb = Pb[p], mm = Pm[p], vv = Pv[p];
#pragma unroll
            for (int i = 0; i < TM; ++i)
                Cb[i * ldc + j] = bn_relu32(acc[i][j], gg, bb, mm, vv);
        } else {
#pragma unroll
            for (int i = 0; i < TM; ++i)
                Cb[i * ldc + j] = hard_gate(acc[i][j]);
        }
    }
}

// ---------------------------------------------------------------------------
// Fallback (round-7 fused kernel, pass-verified): used only if ws too small.
// ---------------------------------------------------------------------------
#define FNT 512
template<int CPT, int RPT, int EPI>
__device__ __forceinline__ void flayer(
    const float* __restrict__ I, int ldI, int K,
    const float* __restrict__ Wt, long ldW,
    const float* __restrict__ Pg, const float* __restrict__ Pb,
    const float* __restrict__ Pm, const float* __restrict__ Pv,
    float* __restrict__ O, int ldO, int n, int r0, int rstep)
{
    float acc[CPT][RPT];
#pragma unroll
    for (int c = 0; c < CPT; ++c)
#pragma unroll
        for (int r = 0; r < RPT; ++r) acc[c][r] = 0.0f;
#pragma unroll 2
    for (int k = 0; k < K; k += 4) {
        float4 av[RPT];
#pragma unroll
        for (int r = 0; r < RPT; ++r)
            av[r] = *reinterpret_cast<const float4*>(I + (r0 + r * rstep) * ldI + k);
#pragma unroll
        for (int c = 0; c < CPT; ++c) {
            float4 w = *reinterpret_cast<const float4*>(Wt + (long)(n + c * FNT) * ldW + k);
#pragma unroll
            for (int r = 0; r < RPT; ++r) {
                acc[c][r] = fmaf(av[r].x, w.x, acc[c][r]);
                acc[c][r] = fmaf(av[r].y, w.y, acc[c][r]);
                acc[c][r] = fmaf(av[r].z, w.z, acc[c][r]);
                acc[c][r] = fmaf(av[r].w, w.w, acc[c][r]);
            }
        }
    }
#pragma unroll
    for (int c = 0; c < CPT; ++c) {
        int nn = n + c * FNT;
        if constexpr (EPI == 1) {
            float gg = Pg[nn], bb = Pb[nn], mm = Pm[nn], vv = Pv[nn];
#pragma unroll
            for (int r = 0; r < RPT; ++r)
                O[(r0 + r * rstep) * ldO + nn] = bn_relu32(acc[c][r], gg, bb, mm, vv);
        } else {
#pragma unroll
            for (int r = 0; r < RPT; ++r)
                O[(r0 + r * rstep) * ldO + nn] = hard_gate(acc[c][r]);
        }
    }
}

__global__ __launch_bounds__(FNT, 4)
void tg32_fused(const float* __restrict__ prompt,
    const float* __restrict__ W1, const float* __restrict__ g1, const float* __restrict__ b1, const float* __restrict__ m1, const float* __restrict__ v1,
    const float* __restrict__ W2, const float* __restrict__ g2, const float* __restrict__ b2, const float* __restrict__ m2, const float* __restrict__ v2,
    const float* __restrict__ W3, const float* __restrict__ g3, const float* __restrict__ b3, const float* __restrict__ m3, const float* __restrict__ v3,
    const float* __restrict__ W4, const float* __restrict__ g4, const float* __restrict__ b4, const float* __restrict__ m4, const float* __restrict__ v4,
    const float* __restrict__ We1, const float* __restrict__ We2,
    const float* __restrict__ eg, const float* __restrict__ eb, const float* __restrict__ em, const float* __restrict__ ev,
    float* __restrict__ out)
{
    __shared__ __align__(16) float arena[12288];
    float* A0 = arena;
    float* A1 = arena + 4096;
    const int t = threadIdx.x;
    const long row0 = (long)blockIdx.x * 8;
    for (int i = t; i < 1024; i += FNT) {
        int r = i >> 7, c4 = (i & 127) << 2;
        *reinterpret_cast<float4*>(A0 + r * 512 + c4) =
            *reinterpret_cast<const float4*>(prompt + (row0 + r) * 512 + c4);
    }
    __syncthreads();
    flayer<1, 1, 1>(A0, 512, 512, W1, 512, g1, b1, m1, v1, A1, 64, t & 63, t >> 6, 1);
    __syncthreads();
    flayer<1, 8, 1>(A1, 64, 64, W2, 64, g2, b2, m2, v2, A0, 512, t, 0, 1);
    __syncthreads();
    flayer<2, 8, 1>(A0, 512, 512, W3, 512, g3, b3, m3, v3, A1, 1024, t, 0, 1);
    __syncthreads();
    flayer<1, 8, 1>(A1, 1024, 1024, W4, 1024, g4, b4, m4, v4, A0, 512, t, 0, 1);
    __syncthreads();
    for (int g = 0; g < 8; ++g) {
        flayer<1, 4, 1>(A0 + g * 64, 512, 64, We1, 64,
                        eg + g * 256, eb + g * 256, em + g * 256, ev + g * 256,
                        A1, 256, t & 255, (t >> 8) * 4, 1);
        __syncthreads();
        flayer<1, 1, 2>(A1, 256, 256, We2, 256, nullptr, nullptr, nullptr, nullptr,
                        out + row0 * 512 + g * 64, 512, t & 63, t >> 6, 1);
        __syncthreads();
    }
}

extern "C" void kernel_launch(void* const* d_in, const int* in_sizes, int n_in,
                              void* d_out, int out_size, void* d_ws, size_t ws_size,
                              hipStream_t stream) {
    (void)n_in; (void)out_size;
    const float* prompt = (const float*)d_in[0];
    const float* W1 = (const float*)d_in[1];
    const float* g1 = (const float*)d_in[2];
    const float* b1 = (const float*)d_in[3];
    const float* m1 = (const float*)d_in[4];
    const float* v1 = (const float*)d_in[5];
    const float* W2 = (const float*)d_in[6];
    const float* g2 = (const float*)d_in[7];
    const float* b2 = (const float*)d_in[8];
    const float* m2 = (const float*)d_in[9];
    const float* v2 = (const float*)d_in[10];
    const float* W3 = (const float*)d_in[11];
    const float* g3 = (const float*)d_in[12];
    const float* b3 = (const float*)d_in[13];
    const float* m3 = (const float*)d_in[14];
    const float* v3 = (const float*)d_in[15];
    const float* W4 = (const float*)d_in[16];
    const float* g4 = (const float*)d_in[17];
    const float* b4 = (const float*)d_in[18];
    const float* m4 = (const float*)d_in[19];
    const float* v4 = (const float*)d_in[20];
    const float* We1 = (const float*)d_in[21];
    const float* We2 = (const float*)d_in[22];
    const float* eg = (const float*)d_in[23];
    const float* eb = (const float*)d_in[24];
    const float* em = (const float*)d_in[25];
    const float* ev = (const float*)d_in[26];
    float* out = (float*)d_out;

    const long Btot = in_sizes[0] / 512;          // 16384
    // Per-row ws footprint: h1 64 + h2 512 + h3 1024 + h4 512 + x 2048 = 4160 f
    const long perRow = 4160;
    long Bc = (long)(ws_size / (perRow * 4));
    if (Bc > Btot) Bc = Btot;
    Bc &= ~127L;                                   // multiple of BM=128

    if (Bc < 128) {
        // ws too small: round-7 fused fallback (pass-verified, ~2.5 ms)
        tg32_fused<<<dim3(Btot / 8), dim3(FNT), 0, stream>>>(prompt,
            W1, g1, b1, m1, v1, W2, g2, b2, m2, v2,
            W3, g3, b3, m3, v3, W4, g4, b4, m4, v4,
            We1, We2, eg, eb, em, ev, out);
        return;
    }

    float* h1 = (float*)d_ws;                      // [Bc,64]
    float* h2 = h1 + Bc * 64;                      // [Bc,512]
    float* h3 = h2 + Bc * 512;                     // [Bc,1024]
    float* h4 = h3 + Bc * 1024;                    // [Bc,512]
    float* x1 = h4 + Bc * 512;                     // [Bc,8,256]

    for (long b0 = 0; b0 < Btot; b0 += Bc) {
        long mc = Btot - b0; if (mc > Bc) mc = Bc;  // multiple of 128
        const float* P = prompt + b0 * 512;
        dim3 blk(256);
        // L1: [mc,512] -> [mc,64]
        gemm_lbr<128, 64, 8, 4, 1><<<dim3(1, mc / 128, 1), blk, 0, stream>>>(
            P, 512, 0, W1, 512, g1, b1, m1, v1, 0, h1, 64, 0, 512);
        // L2: [mc,64] -> [mc,512]
        gemm_lbr<128, 128, 8, 8, 1><<<dim3(4, mc / 128, 1), blk, 0, stream>>>(
            h1, 64, 0, W2, 64, g2, b2, m2, v2, 0, h2, 512, 0, 64);
        // L3: [mc,512] -> [mc,1024]
        gemm_lbr<128, 128, 8, 8, 1><<<dim3(8, mc / 128, 1), blk, 0, stream>>>(
            h2, 512, 0, W3, 512, g3, b3, m3, v3, 0, h3, 1024, 0, 512);
        // L4: [mc,1024] -> [mc,512]
        gemm_lbr<128, 128, 8, 8, 1><<<dim3(4, mc / 128, 1), blk, 0, stream>>>(
            h3, 1024, 0, W4, 1024, g4, b4, m4, v4, 0, h4, 512, 0, 1024);
        // L5: per g (z): [mc,64] -> [mc,256], expert-0 BN row g
        gemm_lbr<128, 128, 8, 8, 1><<<dim3(2, mc / 128, 8), blk, 0, stream>>>(
            h4, 512, 64, We1, 64, eg, eb, em, ev, 256, x1, 2048, 256, 64);
        // L6: per g (z): [mc,256] -> gate -> out[:, g*64..)
        gemm_lbr<128, 64, 8, 4, 2><<<dim3(1, mc / 128, 8), blk, 0, stream>>>(
            x1, 2048, 256, We2, 256, nullptr, nullptr, nullptr, nullptr, 0,
            out + b0 * 512, 512, 64, 256);
    }
}

// Round 9
// 623.116 us; speedup vs baseline: 4.2954x; 2.0097x over previous
//
#include <hip/hip_runtime.h>
#include <cmath>

// ---------------------------------------------------------------------------
// Verified bit-exact numerics (r5-r8): fp32, uncontracted, correctly-rounded
// sqrt/div/exp via fp64 helpers; ascending-k single-accumulator fmaf chains.
// ---------------------------------------------------------------------------
__device__ __forceinline__ float bn_relu32(float h, float g, float b, float m, float v) {
#pragma clang fp contract(off)
    float vp = v + 1e-5f;
    float sq = (float)sqrt((double)vp);
    float rs = (float)(1.0 / (double)sq);
    float t = ((h - m) * rs) * g + b;
    return fmaxf(t, 0.0f);
}

__device__ __forceinline__ float hard_gate(float x) {
#pragma clang fp contract(off)
    float e = (float)exp((double)(-x));
    float d = 1.0f + e;
    float sg = (float)(1.0 / (double)d);
    float s = 1.2f * sg - 0.1f;
    s = fminf(fmaxf(s, 0.0f), 1.0f);
    return (s > 0.49999f) ? 1.0f : 0.0f;
}

// ---------------------------------------------------------------------------
// Tiled fp32 GEMM + fused BN/ReLU epilogue. C[m][n] = epi( A[m][:] . W[n][:] )
// 256 threads, BK=16. Thread owns TM rows x TN cols; TN=8 cols are split as
// two float4 groups {tx*4, BN/2+tx*4} -> Bs reads are 16 distinct float4 in
// 256B = 2-way bank alias (free); TN=4 is a single group. Per-output
// accumulation: single accumulator, strictly ascending k (bit-exact recipe).
// ---------------------------------------------------------------------------
template<int BM, int BN, int TM, int TN>
__global__ __launch_bounds__(256, 4)
void gemm_lbr(const float* __restrict__ A, long lda,
              const float* __restrict__ W, long ldw,
              const float* __restrict__ Pg, const float* __restrict__ Pb,
              const float* __restrict__ Pm, const float* __restrict__ Pv,
              float* __restrict__ C, long ldc, int K)
{
    constexpr int BK = 16, PAD = 4, NT = 256;
    constexpr int NX = BN / TN;
    __shared__ float As[BK][BM + PAD];
    __shared__ float Bs[BK][BN + PAD];

    const int t = threadIdx.x;
    const long m0 = (long)blockIdx.y * BM;
    const int n0 = blockIdx.x * BN;
    const float* Ab = A + m0 * lda;
    const float* Wb = W + (long)n0 * ldw;

    const int tx = t % NX;
    const int ty = t / NX;

    float acc[TM][TN];
#pragma unroll
    for (int i = 0; i < TM; ++i)
#pragma unroll
        for (int j = 0; j < TN; ++j) acc[i][j] = 0.0f;

    for (int k0 = 0; k0 < K; k0 += BK) {
#pragma unroll
        for (int i = 0; i < (BM * BK) / (4 * NT); ++i) {
            int idx = t + i * NT;
            int m = idx >> 2, kq = (idx & 3) << 2;
            float4 v = *reinterpret_cast<const float4*>(Ab + m * lda + k0 + kq);
            As[kq + 0][m] = v.x; As[kq + 1][m] = v.y;
            As[kq + 2][m] = v.z; As[kq + 3][m] = v.w;
        }
#pragma unroll
        for (int i = 0; i < (BN * BK) / (4 * NT); ++i) {
            int idx = t + i * NT;
            int n = idx >> 2, kq = (idx & 3) << 2;
            float4 v = *reinterpret_cast<const float4*>(Wb + n * ldw + k0 + kq);
            Bs[kq + 0][n] = v.x; Bs[kq + 1][n] = v.y;
            Bs[kq + 2][n] = v.z; Bs[kq + 3][n] = v.w;
        }
        __syncthreads();

#pragma unroll
        for (int kk = 0; kk < BK; ++kk) {
            float a[TM], b[TN];
#pragma unroll
            for (int i = 0; i < TM; i += 4)
                *reinterpret_cast<float4*>(&a[i]) =
                    *reinterpret_cast<const float4*>(&As[kk][ty * TM + i]);
            *reinterpret_cast<float4*>(&b[0]) =
                *reinterpret_cast<const float4*>(&Bs[kk][tx * 4]);
            if constexpr (TN == 8)
                *reinterpret_cast<float4*>(&b[4]) =
                    *reinterpret_cast<const float4*>(&Bs[kk][BN / 2 + tx * 4]);
#pragma unroll
            for (int i = 0; i < TM; ++i)
#pragma unroll
                for (int j = 0; j < TN; ++j)
                    acc[i][j] = fmaf(a[i], b[j], acc[i][j]);
        }
        __syncthreads();
    }

    const long crow = m0 + ty * TM;
#pragma unroll
    for (int h = 0; h < TN / 4; ++h) {
        int nbase = n0 + h * (BN / 2) + tx * 4;
        float gg[4], bb[4], mm[4], vv[4];
#pragma unroll
        for (int j = 0; j < 4; ++j) {
            gg[j] = Pg[nbase + j]; bb[j] = Pb[nbase + j];
            mm[j] = Pm[nbase + j]; vv[j] = Pv[nbase + j];
        }
#pragma unroll
        for (int i = 0; i < TM; ++i) {
            float4 o;
            o.x = bn_relu32(acc[i][h * 4 + 0], gg[0], bb[0], mm[0], vv[0]);
            o.y = bn_relu32(acc[i][h * 4 + 1], gg[1], bb[1], mm[1], vv[1]);
            o.z = bn_relu32(acc[i][h * 4 + 2], gg[2], bb[2], mm[2], vv[2]);
            o.w = bn_relu32(acc[i][h * 4 + 3], gg[3], bb[3], mm[3], vv[3]);
            *reinterpret_cast<float4*>(C + (crow + i) * ldc + nbase) = o;
        }
    }
}

// ---------------------------------------------------------------------------
// Fused expert layers (L5+L6) for one 32-row tile x one gate group g:
//   x = BN_g(ReLU)( h4[:, g*64:+64] @ We1^T )  kept in LDS (transposed),
//   out[:, g*64:+64] = hard_gate( x @ We2^T ).
// Eliminates the 134 MB x1 round-trip. Ascending-k chains preserved.
// ---------------------------------------------------------------------------
#define B5 32
__global__ __launch_bounds__(256, 4)
void expert_fused(const float* __restrict__ h4,
                  const float* __restrict__ We1, const float* __restrict__ We2,
                  const float* __restrict__ eg, const float* __restrict__ eb,
                  const float* __restrict__ em, const float* __restrict__ ev,
                  float* __restrict__ out)
{
    __shared__ float As5[64][B5 + 4];     // h4 slice, transposed [s][m]
    __shared__ float xs[256][B5 + 4];     // x, transposed [h][m]
    __shared__ float Bs[16][256 + 4];     // weight staging (L5: [kk][h], L6: [kh][kk])

    const int t = threadIdx.x;
    const long m0 = (long)blockIdx.x * B5;
    const int g = blockIdx.y;

    // stage h4[m0..+32][g*64..+64] -> As5[s][m]
#pragma unroll
    for (int it = 0; it < 2; ++it) {
        int idx4 = t + it * 256;
        int m = idx4 >> 4, sq = (idx4 & 15) << 2;
        float4 v = *reinterpret_cast<const float4*>(h4 + (m0 + m) * 512 + g * 64 + sq);
        As5[sq + 0][m] = v.x; As5[sq + 1][m] = v.y;
        As5[sq + 2][m] = v.z; As5[sq + 3][m] = v.w;
    }

    // ---- L5: x[32,256], K=64. tx in 0..31 owns cols {tx*2 + c*64}, ty in 0..7 owns rows ty*4..+3
    const int tx = t & 31, ty = t >> 5;
    float acc5[4][8];
#pragma unroll
    for (int i = 0; i < 4; ++i)
#pragma unroll
        for (int j = 0; j < 8; ++j) acc5[i][j] = 0.0f;

    for (int k0 = 0; k0 < 64; k0 += 16) {
        __syncthreads();   // protects As5 stores (first iter) / Bs reads (later iters)
#pragma unroll
        for (int it = 0; it < 4; ++it) {
            int idx4 = t + it * 256;
            int hh = idx4 >> 2, kq = (idx4 & 3) << 2;
            float4 v = *reinterpret_cast<const float4*>(We1 + hh * 64 + k0 + kq);
            Bs[kq + 0][hh] = v.x; Bs[kq + 1][hh] = v.y;
            Bs[kq + 2][hh] = v.z; Bs[kq + 3][hh] = v.w;
        }
        __syncthreads();
#pragma unroll
        for (int kk = 0; kk < 16; ++kk) {
            float a[4];
            *reinterpret_cast<float4*>(a) =
                *reinterpret_cast<const float4*>(&As5[k0 + kk][ty * 4]);
            float b[8];
#pragma unroll
            for (int c = 0; c < 4; ++c)
                *reinterpret_cast<float2*>(&b[c * 2]) =
                    *reinterpret_cast<const float2*>(&Bs[kk][tx * 2 + c * 64]);
#pragma unroll
            for (int i = 0; i < 4; ++i)
#pragma unroll
                for (int j = 0; j < 8; ++j)
                    acc5[i][j] = fmaf(a[i], b[j], acc5[i][j]);
        }
    }
    __syncthreads();

    // BN+ReLU epilogue, store transposed into xs[h][m]
#pragma unroll
    for (int c = 0; c < 4; ++c)
#pragma unroll
        for (int u = 0; u < 2; ++u) {
            int hh = tx * 2 + c * 64 + u;
            long p = (long)g * 256 + hh;
            float gg = eg[p], bb = eb[p], mm = em[p], vv = ev[p];
#pragma unroll
            for (int i = 0; i < 4; ++i)
                xs[hh][ty * 4 + i] = bn_relu32(acc5[i][c * 2 + u], gg, bb, mm, vv);
        }

    // ---- L6: out[32,64], K=256. tx owns cols {tx*2, tx*2+1}, ty owns rows ty*4..+3
    float acc6[4][2];
#pragma unroll
    for (int i = 0; i < 4; ++i) { acc6[i][0] = 0.0f; acc6[i][1] = 0.0f; }

    for (int k0 = 0; k0 < 256; k0 += 16) {
        __syncthreads();   // protects xs stores (first iter) / Bs reads
        {
            int kk = t >> 2, khq = (t & 3) << 2;
            float4 v = *reinterpret_cast<const float4*>(We2 + kk * 256 + k0 + khq);
            Bs[khq + 0][kk] = v.x; Bs[khq + 1][kk] = v.y;
            Bs[khq + 2][kk] = v.z; Bs[khq + 3][kk] = v.w;
        }
        __syncthreads();
#pragma unroll
        for (int kh = 0; kh < 16; ++kh) {
            float a[4];
            *reinterpret_cast<float4*>(a) =
                *reinterpret_cast<const float4*>(&xs[k0 + kh][ty * 4]);
            float2 b = *reinterpret_cast<const float2*>(&Bs[kh][tx * 2]);
#pragma unroll
            for (int i = 0; i < 4; ++i) {
                acc6[i][0] = fmaf(a[i], b.x, acc6[i][0]);
                acc6[i][1] = fmaf(a[i], b.y, acc6[i][1]);
            }
        }
    }

#pragma unroll
    for (int i = 0; i < 4; ++i) {
        float2 o;
        o.x = hard_gate(acc6[i][0]);
        o.y = hard_gate(acc6[i][1]);
        *reinterpret_cast<float2*>(out + (m0 + ty * 4 + i) * 512 + g * 64 + tx * 2) = o;
    }
}

// ---------------------------------------------------------------------------
// Fallback (round-7 fused kernel, pass-verified): used only if ws too small.
// ---------------------------------------------------------------------------
#define FNT 512
template<int CPT, int RPT, int EPI>
__device__ __forceinline__ void flayer(
    const float* __restrict__ I, int ldI, int K,
    const float* __restrict__ Wt, long ldW,
    const float* __restrict__ Pg, const float* __restrict__ Pb,
    const float* __restrict__ Pm, const float* __restrict__ Pv,
    float* __restrict__ O, int ldO, int n, int r0, int rstep)
{
    float acc[CPT][RPT];
#pragma unroll
    for (int c = 0; c < CPT; ++c)
#pragma unroll
        for (int r = 0; r < RPT; ++r) acc[c][r] = 0.0f;
#pragma unroll 2
    for (int k = 0; k < K; k += 4) {
        float4 av[RPT];
#pragma unroll
        for (int r = 0; r < RPT; ++r)
            av[r] = *reinterpret_cast<const float4*>(I + (r0 + r * rstep) * ldI + k);
#pragma unroll
        for (int c = 0; c < CPT; ++c) {
            float4 w = *reinterpret_cast<const float4*>(Wt + (long)(n + c * FNT) * ldW + k);
#pragma unroll
            for (int r = 0; r < RPT; ++r) {
                acc[c][r] = fmaf(av[r].x, w.x, acc[c][r]);
                acc[c][r] = fmaf(av[r].y, w.y, acc[c][r]);
                acc[c][r] = fmaf(av[r].z, w.z, acc[c][r]);
                acc[c][r] = fmaf(av[r].w, w.w, acc[c][r]);
            }
        }
    }
#pragma unroll
    for (int c = 0; c < CPT; ++c) {
        int nn = n + c * FNT;
        if constexpr (EPI == 1) {
            float gg = Pg[nn], bb = Pb[nn], mm = Pm[nn], vv = Pv[nn];
#pragma unroll
            for (int r = 0; r < RPT; ++r)
                O[(r0 + r * rstep) * ldO + nn] = bn_relu32(acc[c][r], gg, bb, mm, vv);
        } else {
#pragma unroll
            for (int r = 0; r < RPT; ++r)
                O[(r0 + r * rstep) * ldO + nn] = hard_gate(acc[c][r]);
        }
    }
}

__global__ __launch_bounds__(FNT, 4)
void tg32_fused(const float* __restrict__ prompt,
    const float* __restrict__ W1, const float* __restrict__ g1, const float* __restrict__ b1, const float* __restrict__ m1, const float* __restrict__ v1,
    const float* __restrict__ W2, const float* __restrict__ g2, const float* __restrict__ b2, const float* __restrict__ m2, const float* __restrict__ v2,
    const float* __restrict__ W3, const float* __restrict__ g3, const float* __restrict__ b3, const float* __restrict__ m3, const float* __restrict__ v3,
    const float* __restrict__ W4, const float* __restrict__ g4, const float* __restrict__ b4, const float* __restrict__ m4, const float* __restrict__ v4,
    const float* __restrict__ We1, const float* __restrict__ We2,
    const float* __restrict__ eg, const float* __restrict__ eb, const float* __restrict__ em, const float* __restrict__ ev,
    float* __restrict__ out)
{
    __shared__ __align__(16) float arena[12288];
    float* A0 = arena;
    float* A1 = arena + 4096;
    const int t = threadIdx.x;
    const long row0 = (long)blockIdx.x * 8;
    for (int i = t; i < 1024; i += FNT) {
        int r = i >> 7, c4 = (i & 127) << 2;
        *reinterpret_cast<float4*>(A0 + r * 512 + c4) =
            *reinterpret_cast<const float4*>(prompt + (row0 + r) * 512 + c4);
    }
    __syncthreads();
    flayer<1, 1, 1>(A0, 512, 512, W1, 512, g1, b1, m1, v1, A1, 64, t & 63, t >> 6, 1);
    __syncthreads();
    flayer<1, 8, 1>(A1, 64, 64, W2, 64, g2, b2, m2, v2, A0, 512, t, 0, 1);
    __syncthreads();
    flayer<2, 8, 1>(A0, 512, 512, W3, 512, g3, b3, m3, v3, A1, 1024, t, 0, 1);
    __syncthreads();
    flayer<1, 8, 1>(A1, 1024, 1024, W4, 1024, g4, b4, m4, v4, A0, 512, t, 0, 1);
    __syncthreads();
    for (int g = 0; g < 8; ++g) {
        flayer<1, 4, 1>(A0 + g * 64, 512, 64, We1, 64,
                        eg + g * 256, eb + g * 256, em + g * 256, ev + g * 256,
                        A1, 256, t & 255, (t >> 8) * 4, 1);
        __syncthreads();
        flayer<1, 1, 2>(A1, 256, 256, We2, 256, nullptr, nullptr, nullptr, nullptr,
                        out + row0 * 512 + g * 64, 512, t & 63, t >> 6, 1);
        __syncthreads();
    }
}

extern "C" void kernel_launch(void* const* d_in, const int* in_sizes, int n_in,
                              void* d_out, int out_size, void* d_ws, size_t ws_size,
                              hipStream_t stream) {
    (void)n_in; (void)out_size;
    const float* prompt = (const float*)d_in[0];
    const float* W1 = (const float*)d_in[1];
    const float* g1 = (const float*)d_in[2];
    const float* b1 = (const float*)d_in[3];
    const float* m1 = (const float*)d_in[4];
    const float* v1 = (const float*)d_in[5];
    const float* W2 = (const float*)d_in[6];
    const float* g2 = (const float*)d_in[7];
    const float* b2 = (const float*)d_in[8];
    const float* m2 = (const float*)d_in[9];
    const float* v2 = (const float*)d_in[10];
    const float* W3 = (const float*)d_in[11];
    const float* g3 = (const float*)d_in[12];
    const float* b3 = (const float*)d_in[13];
    const float* m3 = (const float*)d_in[14];
    const float* v3 = (const float*)d_in[15];
    const float* W4 = (const float*)d_in[16];
    const float* g4 = (const float*)d_in[17];
    const float* b4 = (const float*)d_in[18];
    const float* m4 = (const float*)d_in[19];
    const float* v4 = (const float*)d_in[20];
    const float* We1 = (const float*)d_in[21];
    const float* We2 = (const float*)d_in[22];
    const float* eg = (const float*)d_in[23];
    const float* eb = (const float*)d_in[24];
    const float* em = (const float*)d_in[25];
    const float* ev = (const float*)d_in[26];
    float* out = (float*)d_out;

    const long Btot = in_sizes[0] / 512;          // 16384
    // Per-row ws: h1 64 + h2 512 + h3 1024 + h4 512 = 2112 floats (x1 gone)
    const long perRow = 2112;
    long Bc = (long)(ws_size / (perRow * 4));
    if (Bc > Btot) Bc = Btot;
    Bc &= ~127L;                                   // multiple of BM=128

    if (Bc < 128) {
        tg32_fused<<<dim3(Btot / 8), dim3(FNT), 0, stream>>>(prompt,
            W1, g1, b1, m1, v1, W2, g2, b2, m2, v2,
            W3, g3, b3, m3, v3, W4, g4, b4, m4, v4,
            We1, We2, eg, eb, em, ev, out);
        return;
    }

    float* h1 = (float*)d_ws;                      // [Bc,64]
    float* h2 = h1 + Bc * 64;                      // [Bc,512]
    float* h3 = h2 + Bc * 512;                     // [Bc,1024]
    float* h4 = h3 + Bc * 1024;                    // [Bc,512]

    for (long b0 = 0; b0 < Btot; b0 += Bc) {
        long mc = Btot - b0; if (mc > Bc) mc = Bc;
        const float* P = prompt + b0 * 512;
        dim3 blk(256);
        // L1: [mc,512] -> [mc,64]   grid 256 at full batch
        gemm_lbr<64, 64, 4, 4><<<dim3(1, mc / 64), blk, 0, stream>>>(
            P, 512, W1, 512, g1, b1, m1, v1, h1, 64, 512);
        // L2: [mc,64] -> [mc,512]
        gemm_lbr<128, 128, 8, 8><<<dim3(4, mc / 128), blk, 0, stream>>>(
            h1, 64, W2, 64, g2, b2, m2, v2, h2, 512, 64);
        // L3: [mc,512] -> [mc,1024]
        gemm_lbr<128, 128, 8, 8><<<dim3(8, mc / 128), blk, 0, stream>>>(
            h2, 512, W3, 512, g3, b3, m3, v3, h3, 1024, 512);
        // L4: [mc,1024] -> [mc,512]
        gemm_lbr<128, 128, 8, 8><<<dim3(4, mc / 128), blk, 0, stream>>>(
            h3, 1024, W4, 1024, g4, b4, m4, v4, h4, 512, 1024);
        // L5+L6 fused: h4 -> gate -> out   (grid mc/32 x 8)
        expert_fused<<<dim3(mc / 32, 8), blk, 0, stream>>>(
            h4, We1, We2, eg, eb, em, ev, out + b0 * 512);
    }
}